// Round 3
// baseline (233.937 us; speedup 1.0000x reference)
//
#include <hip/hip_runtime.h>

// Problem constants (HyperNetwork_9990093931021)
#define BB 256   // batch
#define CC 512   // channels
#define NZ 256   // flattened spatial (16*16)
#define ZD 64    // z_dim
#define KK 9     // out_c * f * f = 1*3*3
#define WFSZ (KK * NZ)   // fused weight floats per channel = 2304

// ---- DPP cross-lane add helpers (VALU-only) ----
template<int CTRL>
__device__ __forceinline__ float dpp_add(float v) {
    int o = __builtin_amdgcn_update_dpp(0, __float_as_int(v), CTRL, 0xF, 0xF, true);
    return v + __int_as_float(o);
}
__device__ __forceinline__ float red8(float v) {
    v = dpp_add<0xB1>(v);   // xor 1 (quad_perm [1,0,3,2])
    v = dpp_add<0x4E>(v);   // xor 2 (quad_perm [2,3,0,1])
    v = dpp_add<0x141>(v);  // row_half_mirror (combine quads of the 8-lane half)
    return v;
}

// ---- Kernel A: fused weight + fused bias into workspace ----
// Wf[c][k][n] = sum_z W_in[c,n,z] * W_out[z,k]
// biask[c][k] = b_in[c,:] . W_out[:,k] + b_out[k]
__global__ __launch_bounds__(512, 2)
void wf_kernel(const float* __restrict__ W_in, const float* __restrict__ b_in,
               const float* __restrict__ W_out, const float* __restrict__ b_out,
               float* __restrict__ wf, float* __restrict__ biask) {
    __shared__ __align__(16) float s_woutT[KK * ZD]; // [k][z]
    __shared__ float s_bin[ZD];
    const int c = blockIdx.x;
    const int t = threadIdx.x;

    for (int i = t; i < KK * ZD; i += 512) {
        float v = W_out[i];                           // coalesced
        int zz = i / KK, k = i - zz * KK;
        s_woutT[k * ZD + zz] = v;
    }
    if (t < ZD) s_bin[t] = b_in[c * ZD + t];
    __syncthreads();

    const int n = t >> 1, half = t & 1;               // 2 threads per n, 32 z each
    const float* wrow = W_in + ((size_t)c * NZ + n) * ZD + half * 32;
    float acc[KK];
#pragma unroll
    for (int k = 0; k < KK; ++k) acc[k] = 0.f;
#pragma unroll
    for (int j = 0; j < 8; ++j) {
        const float4 w = *reinterpret_cast<const float4*>(wrow + 4 * j);
#pragma unroll
        for (int k = 0; k < KK; ++k) {
            const float4 wo = *reinterpret_cast<const float4*>(
                &s_woutT[k * ZD + half * 32 + 4 * j]);
            acc[k] += w.x * wo.x + w.y * wo.y + w.z * wo.z + w.w * wo.w;
        }
    }
#pragma unroll
    for (int k = 0; k < KK; ++k) acc[k] = dpp_add<0xB1>(acc[k]); // half0+half1
    if (half == 0) {
#pragma unroll
        for (int k = 0; k < KK; ++k)
            wf[(size_t)c * WFSZ + k * NZ + n] = acc[k];
    }
    if (t < KK) {
        float s = 0.f;
        for (int zz = 0; zz < ZD; ++zz) s += s_bin[zz] * s_woutT[t * ZD + zz];
        biask[c * KK + t] = s + b_out[t];
    }
}

// ---- Kernel B: out[b,c,k] = z[b,c,:] . Wf[c][k][:] + biask[c][k] ----
// grid = 4 b-chunks x 512 c (c-major: consecutive blocks share a b-range ->
// contiguous z sweep across the dispatch front). block = 256 = 4 waves.
// 8-lane group owns 2 consecutive b with ALL 16 z float4 loads issued up
// front (full MLP, one HBM-latency exposure per block).
__global__ __launch_bounds__(256, 2)
void out_kernel(const float* __restrict__ z, const float* __restrict__ wf,
                const float* __restrict__ biask, float* __restrict__ out) {
    __shared__ __align__(16) float s_wf[WFSZ];  // [k][n], 9216 B
    __shared__ float s_bias[KK];

    const int cid = blockIdx.x & (CC - 1);
    const int chunk = blockIdx.x >> 9;          // 0..3, 64 b each
    const int t = threadIdx.x;
    const int lane = t & 63;
    const int wave = t >> 6;
    const int g = lane >> 3;
    const int sub = lane & 7;
    const int b0 = chunk * 64 + wave * 16 + g * 2;

    // issue the z preload FIRST (independent of LDS staging -> overlaps it)
    const size_t bstr = (size_t)CC * NZ;
    const float* xp = z + ((size_t)b0 * CC + cid) * NZ + sub * 4;
    float4 x0[8], x1[8];
#pragma unroll
    for (int j = 0; j < 8; ++j)   // 8-lane group covers one 128B line per load
        x0[j] = *reinterpret_cast<const float4*>(xp + j * 32);
#pragma unroll
    for (int j = 0; j < 8; ++j)
        x1[j] = *reinterpret_cast<const float4*>(xp + bstr + j * 32);

    // stage Wf[c] (9 KB, L2/L3-hot) + bias
    {
        const float4* wfg = reinterpret_cast<const float4*>(wf + (size_t)cid * WFSZ);
        float4* s4 = reinterpret_cast<float4*>(s_wf);
        for (int i = t; i < WFSZ / 4; i += 256) s4[i] = wfg[i];
        if (t < KK) s_bias[t] = biask[cid * KK + t];
    }
    __syncthreads();

    float a0[KK], a1[KK];
#pragma unroll
    for (int k = 0; k < KK; ++k) { a0[k] = 0.f; a1[k] = 0.f; }
#pragma unroll
    for (int k = 0; k < KK; ++k) {
#pragma unroll
        for (int j = 0; j < 8; ++j) {
            const float4 wfv = *reinterpret_cast<const float4*>(
                &s_wf[k * NZ + sub * 4 + j * 32]);  // 128B span + group broadcast
            a0[k] += x0[j].x * wfv.x + x0[j].y * wfv.y + x0[j].z * wfv.z + x0[j].w * wfv.w;
            a1[k] += x1[j].x * wfv.x + x1[j].y * wfv.y + x1[j].z * wfv.z + x1[j].w * wfv.w;
        }
    }
#pragma unroll
    for (int k = 0; k < KK; ++k) { a0[k] = red8(a0[k]); a1[k] = red8(a1[k]); }

    const float biasS = s_bias[sub];
    float v0 = a0[0], v1 = a1[0];
#pragma unroll
    for (int k = 1; k < 8; ++k) {
        if (sub == k) { v0 = a0[k]; v1 = a1[k]; }   // cndmask chain
    }
    const size_t o0 = ((size_t)b0 * CC + cid) * KK;
    const size_t o1 = o0 + (size_t)CC * KK;
    out[o0 + sub] = v0 + biasS;
    out[o1 + sub] = v1 + biasS;
    if (sub == 0) {
        out[o0 + 8] = a0[8] + s_bias[8];
        out[o1 + 8] = a1[8] + s_bias[8];
    }
}

extern "C" void kernel_launch(void* const* d_in, const int* in_sizes, int n_in,
                              void* d_out, int out_size, void* d_ws, size_t ws_size,
                              hipStream_t stream) {
    const float* z     = (const float*)d_in[0];
    const float* W_in  = (const float*)d_in[1];
    const float* b_in  = (const float*)d_in[2];
    const float* W_out = (const float*)d_in[3];
    const float* b_out = (const float*)d_in[4];
    float* out = (float*)d_out;

    float* wf    = (float*)d_ws;                       // CC*WFSZ floats = 4.7 MB
    float* biask = (float*)d_ws + (size_t)CC * WFSZ;   // CC*KK floats

    wf_kernel<<<dim3(CC), dim3(512), 0, stream>>>(W_in, b_in, W_out, b_out, wf, biask);
    out_kernel<<<dim3(4 * CC), dim3(256), 0, stream>>>(z, wf, biask, out);
}